// Round 3
// baseline (249.251 us; speedup 1.0000x reference)
//
#include <hip/hip_runtime.h>
#include <math.h>

#define BB 64
#define MM 128
#define DDIM 2048
#define KK 32
#define NFR (BB*MM)              // 8192
#define OUTROW (DDIM + KK*DDIM)  // 67584

// ---------------------------------------------------------------------------
// K1: partial logits + partial ssq per frame over a d-chunk of width dcw.
// grid (64 frame-groups of 128, ndc d-chunks) x 256 threads.
// Thread halves split K: t<128 -> clusters 0..15, t>=128 -> 16..31, so serial
// FMA work per wave is halved and grid doubles vs round 2.
// x staged via LDS transposed xs[d][frame] (conflict-free both directions);
// W rows are contiguous wave-uniform (scalar) reads.
// ---------------------------------------------------------------------------
__global__ __launch_bounds__(256) void k_dots(const float* __restrict__ x,
        const int* __restrict__ lengths, const float* __restrict__ W,
        float* __restrict__ part_dots, float* __restrict__ part_ssq, int dcw) {
  __shared__ float xs[32][129];   // [d][frame 0..127]
  const int t  = threadIdx.x;
  const int fg = blockIdx.x;      // 0..63  (128 frames each)
  const int dc = blockIdx.y;      // 0..ndc-1
  const int g0 = fg * 128;
  const int d0 = dc * dcw;
  const int sN = dcw >> 5;

  const int fr_st = t >> 3;       // staging frame sub-index 0..31
  const int dq    = t & 7;        // staging float4 column 0..7

  bool va[4];
  #pragma unroll
  for (int i = 0; i < 4; ++i) {
    int g = g0 + i*32 + fr_st;
    va[i] = (g & (MM-1)) < lengths[g >> 7];
  }

  const int frame = t & 127;      // compute frame within group
  const int kh    = (t >> 7) * 16;  // cluster half: 0 or 16

  float acc[16];
  #pragma unroll
  for (int k = 0; k < 16; ++k) acc[k] = 0.f;
  float ssq = 0.f;

  for (int s = 0; s < sN; ++s) {
    const int dbase = d0 + s*32;
    #pragma unroll
    for (int i = 0; i < 4; ++i) {
      int fr = i*32 + fr_st;
      int g  = g0 + fr;
      float4 v = make_float4(0.f, 0.f, 0.f, 0.f);
      if (va[i]) v = *(const float4*)(x + (size_t)g*DDIM + dbase + dq*4);
      xs[dq*4+0][fr] = v.x; xs[dq*4+1][fr] = v.y;
      xs[dq*4+2][fr] = v.z; xs[dq*4+3][fr] = v.w;
    }
    __syncthreads();

    float xv[32];
    #pragma unroll
    for (int dd = 0; dd < 32; ++dd) {
      xv[dd] = xs[dd][frame];
      ssq = fmaf(xv[dd], xv[dd], ssq);
    }

    const float* wp = W + dbase;   // wave-uniform
    #pragma unroll 4
    for (int k = 0; k < 16; ++k) {
      const float* wr = wp + (size_t)(kh + k)*DDIM;  // contiguous, scalar
      float a = acc[k];
      #pragma unroll
      for (int dd = 0; dd < 32; ++dd) a = fmaf(wr[dd], xv[dd], a);
      acc[k] = a;
    }
    __syncthreads();
  }

  const int g = g0 + frame;
  float* po = part_dots + ((size_t)dc*NFR + g)*KK + kh;
  #pragma unroll
  for (int k = 0; k < 16; k += 4)
    *(float4*)(po + k) = make_float4(acc[k], acc[k+1], acc[k+2], acc[k+3]);
  if (kh == 0) part_ssq[(size_t)dc*NFR + g] = ssq;
}

// ---------------------------------------------------------------------------
// K1b: reduce ndc partials, per-frame L2 norm, stable softmax, mask.
// 8 threads per frame (each owns 4 clusters), xor-1/2/4 butterflies.
// grid 256 x 256.
// ---------------------------------------------------------------------------
__global__ __launch_bounds__(256) void k_softmax(const int* __restrict__ lengths,
    const float* __restrict__ part_dots, const float* __restrict__ part_ssq,
    float* __restrict__ aw, float* __restrict__ invn, int ndc) {
  const int t  = threadIdx.x;
  const int gt = blockIdx.x*256 + t;
  const int g  = gt >> 3;          // frame 0..8191
  const int q  = t & 7;            // octet lane
  const int b  = g >> 7, m = g & (MM-1);

  float s[4];
  #pragma unroll
  for (int i = 0; i < 4; ++i) s[i] = 0.f;
  for (int c = 0; c < ndc; ++c) {
    float4 v = *(const float4*)(part_dots + ((size_t)c*NFR + g)*KK + q*4);
    s[0]+=v.x; s[1]+=v.y; s[2]+=v.z; s[3]+=v.w;
  }
  float ssq = 0.f;
  for (int c = q; c < ndc; c += 8) ssq += part_ssq[(size_t)c*NFR + g];
  ssq += __shfl_xor(ssq, 1, 64);
  ssq += __shfl_xor(ssq, 2, 64);
  ssq += __shfl_xor(ssq, 4, 64);

  float inv = 1.f / fmaxf(sqrtf(ssq), 1e-12f);
  if (q == 0) invn[g] = inv;

  float mx = -1e30f;
  #pragma unroll
  for (int i = 0; i < 4; ++i) { s[i] *= inv; mx = fmaxf(mx, s[i]); }
  mx = fmaxf(mx, __shfl_xor(mx, 1, 64));
  mx = fmaxf(mx, __shfl_xor(mx, 2, 64));
  mx = fmaxf(mx, __shfl_xor(mx, 4, 64));
  float se = 0.f;
  #pragma unroll
  for (int i = 0; i < 4; ++i) { s[i] = __expf(s[i] - mx); se += s[i]; }
  se += __shfl_xor(se, 1, 64);
  se += __shfl_xor(se, 2, 64);
  se += __shfl_xor(se, 4, 64);

  const bool valid = m < lengths[b];
  float r = valid ? (1.f / se) : 0.f;
  *(float4*)(aw + (size_t)g*KK + q*4) =
      make_float4(s[0]*r, s[1]*r, s[2]*r, s[3]*r);
}

// ---------------------------------------------------------------------------
// K2: vlad accumulation. grid (8 d-chunks, 64 b, 2 k-halves) x 256 threads
// = 1024 blocks (4/CU). Thread owns 1 d-column, 16 clusters.
// Depth-8 register prefetch pipeline on the x column walk (8 loads in
// flight/lane); boundary handled by index clamp + mask multiply, no branches.
// a-row and invn loads are wave-uniform -> scalar.
// ---------------------------------------------------------------------------
__global__ __launch_bounds__(256) void k_vlad(const float* __restrict__ x,
    const int* __restrict__ lengths, const float* __restrict__ Cc,
    const float* __restrict__ aw, const float* __restrict__ invn,
    float* __restrict__ out, float* __restrict__ ssq_part) {
  const int t  = threadIdx.x;
  const int dc = blockIdx.x;     // 0..7
  const int b  = blockIdx.y;     // 0..63
  const int ks = blockIdx.z;     // 0..1
  const int d  = dc*256 + t;
  const int k0 = ks*16;
  const int len = lengths[b];
  const int lm1 = len - 1;

  __shared__ float asred[16][16];  // [slice][k-local]; addr==t, conflict-free
  __shared__ float ssql[4][16];

  { // asum[k0+kq] = sum_m a[b,m,k0+kq]
    int kq = t & 15, sl = t >> 4;
    float p = 0.f;
    for (int m = sl; m < len; m += 16)
      p += aw[(size_t)(b*MM + m)*KK + k0 + kq];
    asred[sl][kq] = p;
  }
  __syncthreads();

  float acc[16];
  #pragma unroll
  for (int k = 0; k < 16; ++k) acc[k] = 0.f;
  float avg = 0.f;

  const float* xcol = x + (size_t)b*MM*DDIM + d;
  const float* arow = aw + (size_t)b*MM*KK + k0;

  float cur[8], nxt[8];
  #pragma unroll
  for (int i = 0; i < 8; ++i) {
    int mi = min(i, lm1);
    cur[i] = xcol[(size_t)mi*DDIM];
  }

  for (int mb = 0; mb < len; mb += 8) {
    #pragma unroll
    for (int i = 0; i < 8; ++i) {
      int mi = min(mb + 8 + i, lm1);
      nxt[i] = xcol[(size_t)mi*DDIM];
    }
    #pragma unroll
    for (int i = 0; i < 8; ++i) {
      int m  = mb + i;
      int mc = min(m, lm1);
      float msk = (m < len) ? 1.f : 0.f;
      float xv  = cur[i] * msk;
      avg += xv;
      float xn = xv * invn[b*MM + mc];          // scalar
      const float* ap = arow + (size_t)mc*KK;   // scalar row
      #pragma unroll
      for (int k = 0; k < 16; ++k)
        acc[k] = fmaf(ap[k], xn, acc[k]);
    }
    #pragma unroll
    for (int i = 0; i < 8; ++i) cur[i] = nxt[i];
  }

  float* orow = out + (size_t)b*OUTROW;
  if (ks == 0) orow[d] = avg / (float)len;

  const int lane = t & 63, w = t >> 6;
  #pragma unroll
  for (int k = 0; k < 16; ++k) {
    float asum = 0.f;
    #pragma unroll
    for (int sl = 0; sl < 16; ++sl) asum += asred[sl][k];
    float v = acc[k] - asum * Cc[(size_t)(k0 + k)*DDIM + d];
    orow[DDIM + (size_t)(k0 + k)*DDIM + d] = v;
    float sq = v*v;
    #pragma unroll
    for (int off = 32; off > 0; off >>= 1)
      sq += __shfl_down(sq, off, 64);
    if (lane == 0) ssql[w][k] = sq;
  }
  __syncthreads();
  if (t < 16) {
    ssq_part[((size_t)dc*BB + b)*KK + k0 + t] =
        ssql[0][t] + ssql[1][t] + ssql[2][t] + ssql[3][t];
  }
}

// ---------------------------------------------------------------------------
// K2b: per-(b,k) final scale = intra-inv-norm * global-inv-norm.
// grid 64 x 32 threads (one half-wave per b).
// ---------------------------------------------------------------------------
__global__ __launch_bounds__(32) void k_scales(const float* __restrict__ ssq_part,
    float* __restrict__ scale) {
  const int b = blockIdx.x;
  const int k = threadIdx.x;   // 0..31
  float sk = 0.f;
  #pragma unroll
  for (int dc = 0; dc < 8; ++dc)
    sk += ssq_part[((size_t)dc*BB + b)*KK + k];
  float nk = sqrtf(sk);
  float iv = 1.f / fmaxf(nk, 1e-12f);
  float nn = nk * iv;
  float g  = nn * nn;
  g += __shfl_xor(g, 1, 32);
  g += __shfl_xor(g, 2, 32);
  g += __shfl_xor(g, 4, 32);
  g += __shfl_xor(g, 8, 32);
  g += __shfl_xor(g, 16, 32);
  float ginv = 1.f / fmaxf(sqrtf(g), 1e-12f);
  scale[(size_t)b*KK + k] = iv * ginv;
}

// ---------------------------------------------------------------------------
// K3: apply scale in place. grid (32 k, 64 b) x 256 threads, 2 float4 each,
// fully coalesced contiguous rows.
// ---------------------------------------------------------------------------
__global__ __launch_bounds__(256) void k_norm(const float* __restrict__ scale,
    float* __restrict__ out) {
  const int t = threadIdx.x;
  const int k = blockIdx.x;
  const int b = blockIdx.y;
  float sc = scale[(size_t)b*KK + k];
  float* row = out + (size_t)b*OUTROW + DDIM + (size_t)k*DDIM;
  #pragma unroll
  for (int h = 0; h < 2; ++h) {
    float4* p = (float4*)(row + h*1024 + t*4);
    float4 v = *p;
    v.x *= sc; v.y *= sc; v.z *= sc; v.w *= sc;
    *p = v;
  }
}

// ---------------------------------------------------------------------------
extern "C" void kernel_launch(void* const* d_in, const int* in_sizes, int n_in,
                              void* d_out, int out_size, void* d_ws, size_t ws_size,
                              hipStream_t stream) {
  const float* x       = (const float*)d_in[0];
  const int*   lengths = (const int*)d_in[1];
  const float* W       = (const float*)d_in[2];
  const float* C       = (const float*)d_in[3];
  float* out = (float*)d_out;

  const size_t fixed = ((size_t)NFR*KK + NFR + 8*(size_t)BB*KK + (size_t)BB*KK) * 4;
  const size_t per   = ((size_t)NFR*KK + NFR) * 4;   // one d-chunk of partials
  int ndc = (ws_size >= fixed + 16*per) ? 16 : 8;
  const int dcw = DDIM / ndc;

  float* ws        = (float*)d_ws;
  float* part_dots = ws;                                  // ndc*NFR*KK
  float* part_ssq  = part_dots + (size_t)ndc*NFR*KK;      // ndc*NFR
  float* aw        = part_ssq  + (size_t)ndc*NFR;         // NFR*KK
  float* invn      = aw        + (size_t)NFR*KK;          // NFR
  float* ssq_part  = invn      + NFR;                     // 8*BB*KK
  float* scale     = ssq_part  + 8*(size_t)BB*KK;         // BB*KK

  k_dots   <<<dim3(64, ndc),  256, 0, stream>>>(x, lengths, W, part_dots, part_ssq, dcw);
  k_softmax<<<dim3(256),      256, 0, stream>>>(lengths, part_dots, part_ssq, aw, invn, ndc);
  k_vlad   <<<dim3(8, 64, 2), 256, 0, stream>>>(x, lengths, C, aw, invn, out, ssq_part);
  k_scales <<<dim3(64),        32, 0, stream>>>(ssq_part, scale);
  k_norm   <<<dim3(32, 64),   256, 0, stream>>>(scale, out);
}

// Round 4
// 191.516 us; speedup vs baseline: 1.3015x; 1.3015x over previous
//
#include <hip/hip_runtime.h>
#include <math.h>

#define BB 64
#define MM 128
#define DDIM 2048
#define KK 32
#define NFR (BB*MM)              // 8192
#define OUTROW (DDIM + KK*DDIM)  // 67584

// ---------------------------------------------------------------------------
// K1: logits partials + ssq partials over a d-chunk of width SN*32.
// grid (32 frame-groups of 256, ndc) x 256 threads.
// W chunk staged in LDS once per block (inner loop: LDS only, no VMEM).
// x staged transposed xs[d][frame]; thread tile 4 frames x 8 clusters.
// ssq computed during staging (thread squares what it stages; octet
// shuffle-reduce at the end) -- balanced, no divergence.
// ---------------------------------------------------------------------------
template <int SN>
__global__ __launch_bounds__(256) void k_dots(const float* __restrict__ x,
    const int* __restrict__ lengths, const float* __restrict__ W,
    float* __restrict__ part_dots, float* __restrict__ part_ssq) {
  constexpr int DCW = SN * 32;
  __shared__ float xs[32][260];    // [d within 32-chunk][frame], 16B-aligned rows
  __shared__ float wl[DCW][32];    // [d local][k]
  const int t  = threadIdx.x;
  const int fg = blockIdx.x;       // 0..31
  const int dc = blockIdx.y;       // 0..ndc-1
  const int g0 = fg * 256;
  const int d0 = dc * DCW;

  // ---- stage W chunk (one-time): global [k][d] -> LDS [d][k]
  #pragma unroll
  for (int it = 0; it < DCW / 32; ++it) {
    int idx = it * 256 + t;              // float4 index over [32][DCW/4]
    int k   = idx / (DCW / 4);
    int dl  = (idx % (DCW / 4)) * 4;
    float4 v = *(const float4*)(W + (size_t)k * DDIM + d0 + dl);
    wl[dl + 0][k] = v.x; wl[dl + 1][k] = v.y;
    wl[dl + 2][k] = v.z; wl[dl + 3][k] = v.w;
  }

  const int fr_st = t >> 3;        // staging frame sub-index 0..31
  const int dq    = t & 7;         // staging float4 column 0..7
  bool va[8];
  #pragma unroll
  for (int i = 0; i < 8; ++i) {
    int g = g0 + fr_st + 32 * i;
    va[i] = (g & (MM - 1)) < lengths[g >> 7];
  }

  const int fr0 = (t & 63) * 4;    // 4 contiguous frames per thread
  const int kw  = (t >> 6) * 8;    // 8 clusters per thread (wave-uniform)

  float acc[8][4];
  #pragma unroll
  for (int kj = 0; kj < 8; ++kj)
    #pragma unroll
    for (int fj = 0; fj < 4; ++fj) acc[kj][fj] = 0.f;
  float ssq8[8];
  #pragma unroll
  for (int i = 0; i < 8; ++i) ssq8[i] = 0.f;

  for (int s = 0; s < SN; ++s) {
    __syncthreads();   // protect xs from previous iteration's readers
    const float* xp = x + d0 + s * 32 + dq * 4;
    #pragma unroll
    for (int i = 0; i < 8; ++i) {
      int fr = fr_st + 32 * i;
      float4 v = make_float4(0.f, 0.f, 0.f, 0.f);
      if (va[i]) v = *(const float4*)(xp + (size_t)(g0 + fr) * DDIM);
      float s0 = fmaf(v.x, v.x, fmaf(v.y, v.y, fmaf(v.z, v.z, v.w * v.w)));
      ssq8[i] += s0;
      xs[dq * 4 + 0][fr] = v.x; xs[dq * 4 + 1][fr] = v.y;
      xs[dq * 4 + 2][fr] = v.z; xs[dq * 4 + 3][fr] = v.w;
    }
    __syncthreads();   // also covers the one-time W staging before first use

    #pragma unroll
    for (int dd = 0; dd < 32; ++dd) {
      float4 xv = *(const float4*)&xs[dd][fr0];               // contiguous b128
      float4 w0 = *(const float4*)&wl[s * 32 + dd][kw];       // broadcast b128
      float4 w1 = *(const float4*)&wl[s * 32 + dd][kw + 4];   // broadcast b128
      float wv[8] = {w0.x, w0.y, w0.z, w0.w, w1.x, w1.y, w1.z, w1.w};
      float xf[4] = {xv.x, xv.y, xv.z, xv.w};
      #pragma unroll
      for (int kj = 0; kj < 8; ++kj)
        #pragma unroll
        for (int fj = 0; fj < 4; ++fj)
          acc[kj][fj] = fmaf(wv[kj], xf[fj], acc[kj][fj]);
    }
  }

  // ---- write logits partials: frames g0+fr0..+3, clusters kw..kw+7
  #pragma unroll
  for (int fj = 0; fj < 4; ++fj) {
    float* po = part_dots + ((size_t)dc * NFR + g0 + fr0 + fj) * KK + kw;
    *(float4*)po = make_float4(acc[0][fj], acc[1][fj], acc[2][fj], acc[3][fj]);
    *(float4*)(po + 4) =
        make_float4(acc[4][fj], acc[5][fj], acc[6][fj], acc[7][fj]);
  }
  // ---- ssq: reduce across the 8 dq lanes of each octet
  #pragma unroll
  for (int i = 0; i < 8; ++i) {
    float sv = ssq8[i];
    sv += __shfl_xor(sv, 1, 64);
    sv += __shfl_xor(sv, 2, 64);
    sv += __shfl_xor(sv, 4, 64);
    ssq8[i] = sv;
  }
  if (dq == 0) {
    #pragma unroll
    for (int i = 0; i < 8; ++i)
      part_ssq[(size_t)dc * NFR + g0 + fr_st + 32 * i] = ssq8[i];
  }
}

// ---------------------------------------------------------------------------
// K1b: reduce ndc partials, per-frame L2 norm, stable softmax, mask.
// 8 threads per frame, xor butterflies. grid 256 x 256.
// ---------------------------------------------------------------------------
__global__ __launch_bounds__(256) void k_softmax(const int* __restrict__ lengths,
    const float* __restrict__ part_dots, const float* __restrict__ part_ssq,
    float* __restrict__ aw, float* __restrict__ invn, int ndc) {
  const int t  = threadIdx.x;
  const int gt = blockIdx.x * 256 + t;
  const int g  = gt >> 3;
  const int q  = t & 7;
  const int b  = g >> 7, m = g & (MM - 1);

  float s[4] = {0.f, 0.f, 0.f, 0.f};
  for (int c = 0; c < ndc; ++c) {
    float4 v = *(const float4*)(part_dots + ((size_t)c * NFR + g) * KK + q * 4);
    s[0] += v.x; s[1] += v.y; s[2] += v.z; s[3] += v.w;
  }
  float ssq = 0.f;
  for (int c = q; c < ndc; c += 8) ssq += part_ssq[(size_t)c * NFR + g];
  ssq += __shfl_xor(ssq, 1, 64);
  ssq += __shfl_xor(ssq, 2, 64);
  ssq += __shfl_xor(ssq, 4, 64);

  float inv = 1.f / fmaxf(sqrtf(ssq), 1e-12f);
  if (q == 0) invn[g] = inv;

  float mx = -1e30f;
  #pragma unroll
  for (int i = 0; i < 4; ++i) { s[i] *= inv; mx = fmaxf(mx, s[i]); }
  mx = fmaxf(mx, __shfl_xor(mx, 1, 64));
  mx = fmaxf(mx, __shfl_xor(mx, 2, 64));
  mx = fmaxf(mx, __shfl_xor(mx, 4, 64));
  float se = 0.f;
  #pragma unroll
  for (int i = 0; i < 4; ++i) { s[i] = __expf(s[i] - mx); se += s[i]; }
  se += __shfl_xor(se, 1, 64);
  se += __shfl_xor(se, 2, 64);
  se += __shfl_xor(se, 4, 64);

  const bool valid = m < lengths[b];
  float r = valid ? (1.f / se) : 0.f;
  *(float4*)(aw + (size_t)g * KK + q * 4) =
      make_float4(s[0] * r, s[1] * r, s[2] * r, s[3] * r);
}

// ---------------------------------------------------------------------------
// K2: vlad accumulation. grid (8 d-chunks, 64 b) x 256 threads.
// Whole a-block (128x32) + invn staged in LDS once; inner loop is
// broadcast ds_read_b128 + FMA only, with depth-8 x prefetch pipeline.
// ---------------------------------------------------------------------------
__global__ __launch_bounds__(256) void k_vlad(const float* __restrict__ x,
    const int* __restrict__ lengths, const float* __restrict__ Cc,
    const float* __restrict__ aw, const float* __restrict__ invn,
    float* __restrict__ out, float* __restrict__ ssq_part) {
  const int t  = threadIdx.x;
  const int dc = blockIdx.x;     // 0..7
  const int b  = blockIdx.y;     // 0..63
  const int d  = dc * 256 + t;
  const int len = lengths[b];
  const int lm1 = len - 1;

  __shared__ float al[MM][36];   // a rows, 16B-aligned rows
  __shared__ float il[MM];
  __shared__ float asred[8][32];
  __shared__ float ssql[4][32];

  #pragma unroll
  for (int it = 0; it < 4; ++it) {
    int idx = it * 256 + t;      // 0..1023 float4s over [128][8]
    int m = idx >> 3, kq = (idx & 7) * 4;
    float4 v = *(const float4*)(aw + ((size_t)b * MM + m) * KK + kq);
    *(float4*)&al[m][kq] = v;
  }
  if (t < MM) il[t] = invn[b * MM + t];
  __syncthreads();

  { // asum[k] = sum_m a[b,m,k]  (8 slices then tree in epilogue)
    int k = t & 31, sl = t >> 5;
    float p = 0.f;
    for (int m = sl; m < len; m += 8) p += al[m][k];
    asred[sl][k] = p;
  }

  float acc[32];
  #pragma unroll
  for (int k = 0; k < KK; ++k) acc[k] = 0.f;
  float avg = 0.f;

  const float* xcol = x + (size_t)b * MM * DDIM + d;
  float cur[8], nxt[8];
  #pragma unroll
  for (int i = 0; i < 8; ++i) cur[i] = xcol[(size_t)min(i, lm1) * DDIM];

  for (int mb = 0; mb < len; mb += 8) {
    #pragma unroll
    for (int i = 0; i < 8; ++i)
      nxt[i] = xcol[(size_t)min(mb + 8 + i, lm1) * DDIM];
    #pragma unroll
    for (int i = 0; i < 8; ++i) {
      int m  = mb + i;
      int mc = min(m, lm1);
      float msk = (m < len) ? 1.f : 0.f;
      float xv  = cur[i] * msk;
      avg += xv;
      float xn = xv * il[mc];
      #pragma unroll
      for (int kq = 0; kq < 8; ++kq) {
        float4 av = *(const float4*)&al[mc][kq * 4];   // broadcast b128
        acc[kq*4+0] = fmaf(av.x, xn, acc[kq*4+0]);
        acc[kq*4+1] = fmaf(av.y, xn, acc[kq*4+1]);
        acc[kq*4+2] = fmaf(av.z, xn, acc[kq*4+2]);
        acc[kq*4+3] = fmaf(av.w, xn, acc[kq*4+3]);
      }
    }
    #pragma unroll
    for (int i = 0; i < 8; ++i) cur[i] = nxt[i];
  }

  __syncthreads();   // asred ready
  float* orow = out + (size_t)b * OUTROW;
  orow[d] = avg / (float)len;

  const int lane = t & 63, w = t >> 6;
  #pragma unroll
  for (int k = 0; k < KK; ++k) {
    float asum = 0.f;
    #pragma unroll
    for (int sl = 0; sl < 8; ++sl) asum += asred[sl][k];
    float v = acc[k] - asum * Cc[(size_t)k * DDIM + d];
    orow[DDIM + (size_t)k * DDIM + d] = v;
    float sq = v * v;
    #pragma unroll
    for (int off = 32; off > 0; off >>= 1)
      sq += __shfl_down(sq, off, 64);
    if (lane == 0) ssql[w][k] = sq;
  }
  __syncthreads();
  if (t < KK) {
    ssq_part[((size_t)dc * BB + b) * KK + t] =
        ssql[0][t] + ssql[1][t] + ssql[2][t] + ssql[3][t];
  }
}

// ---------------------------------------------------------------------------
// K3: fused scales + apply. grid (32 k, 64 b) x 256 threads; each block
// recomputes the tiny per-b reduction, then scales one contiguous row.
// ---------------------------------------------------------------------------
__global__ __launch_bounds__(256) void k_norm(const float* __restrict__ ssq_part,
    float* __restrict__ out) {
  const int t = threadIdx.x;
  const int k = blockIdx.x;
  const int b = blockIdx.y;
  __shared__ float ssk[32];
  if (t < 32) {
    float sk = 0.f;
    #pragma unroll
    for (int dc = 0; dc < 8; ++dc)
      sk += ssq_part[((size_t)dc * BB + b) * KK + t];
    ssk[t] = sk;
  }
  __syncthreads();
  float gss = 0.f, iv_own = 0.f;
  #pragma unroll
  for (int kk = 0; kk < 32; ++kk) {
    float nk = sqrtf(ssk[kk]);
    float iv = 1.f / fmaxf(nk, 1e-12f);
    float nn = nk * iv;
    gss += nn * nn;
    if (kk == k) iv_own = iv;
  }
  float sc = iv_own / fmaxf(sqrtf(gss), 1e-12f);
  float* row = out + (size_t)b * OUTROW + DDIM + (size_t)k * DDIM;
  #pragma unroll
  for (int h = 0; h < 2; ++h) {
    float4* p = (float4*)(row + h * 1024 + t * 4);
    float4 v = *p;
    v.x *= sc; v.y *= sc; v.z *= sc; v.w *= sc;
    *p = v;
  }
}

// ---------------------------------------------------------------------------
extern "C" void kernel_launch(void* const* d_in, const int* in_sizes, int n_in,
                              void* d_out, int out_size, void* d_ws, size_t ws_size,
                              hipStream_t stream) {
  const float* x       = (const float*)d_in[0];
  const int*   lengths = (const int*)d_in[1];
  const float* W       = (const float*)d_in[2];
  const float* C       = (const float*)d_in[3];
  float* out = (float*)d_out;

  const size_t fixed = ((size_t)NFR * KK + NFR + 8 * (size_t)BB * KK) * 4;
  const size_t per   = ((size_t)NFR * KK + NFR) * 4;
  const int ndc = (ws_size >= fixed + 32 * per) ? 32 : 16;   // r3 proved 16 fits

  float* ws        = (float*)d_ws;
  float* part_dots = ws;                                 // ndc*NFR*KK
  float* part_ssq  = part_dots + (size_t)ndc * NFR * KK; // ndc*NFR
  float* aw        = part_ssq  + (size_t)ndc * NFR;      // NFR*KK
  float* invn      = aw        + (size_t)NFR * KK;       // NFR
  float* ssq_part  = invn      + NFR;                    // 8*BB*KK

  if (ndc == 32)
    k_dots<2><<<dim3(32, 32), 256, 0, stream>>>(x, lengths, W, part_dots, part_ssq);
  else
    k_dots<4><<<dim3(32, 16), 256, 0, stream>>>(x, lengths, W, part_dots, part_ssq);
  k_softmax<<<dim3(256),   256, 0, stream>>>(lengths, part_dots, part_ssq, aw, invn, ndc);
  k_vlad   <<<dim3(8, 64), 256, 0, stream>>>(x, lengths, C, aw, invn, out, ssq_part);
  k_norm   <<<dim3(32, 64),256, 0, stream>>>(ssq_part, out);
}

// Round 5
// 148.162 us; speedup vs baseline: 1.6823x; 1.2926x over previous
//
#include <hip/hip_runtime.h>
#include <math.h>

#define BB 64
#define MM 128
#define DDIM 2048
#define KK 32
#define NFR (BB*MM)              // 8192
#define OUTROW (DDIM + KK*DDIM)  // 67584

typedef __attribute__((ext_vector_type(8))) short bf16x8;
typedef __attribute__((ext_vector_type(4))) float f32x4;

// float -> bf16 RNE (inputs finite; no NaN handling needed)
__device__ __forceinline__ short f2bf(float f) {
  unsigned u = __builtin_bit_cast(unsigned, f);
  u += 0x7fffu + ((u >> 16) & 1u);
  return (short)(u >> 16);
}

// ---------------------------------------------------------------------------
// K0: W fp32 -> bf16 once. 65536 elems, 32 blocks x 256 x 8.
// ---------------------------------------------------------------------------
__global__ __launch_bounds__(256) void k_prep(const float* __restrict__ W,
                                              short* __restrict__ Wb) {
  int i = (blockIdx.x * 256 + threadIdx.x) * 8;
  float4 a = *(const float4*)(W + i);
  float4 b = *(const float4*)(W + i + 4);
  bf16x8 o = {f2bf(a.x), f2bf(a.y), f2bf(a.z), f2bf(a.w),
              f2bf(b.x), f2bf(b.y), f2bf(b.z), f2bf(b.w)};
  *(bf16x8*)(Wb + i) = o;
}

// ---------------------------------------------------------------------------
// K1: fused logits GEMM (bf16 MFMA) + per-frame ssq + softmax + mask.
// Writes a'T[b][k][m] bf16 (a' = a * invn, exactly the vlad A-frag layout)
// and asum[b][k] fp32 (atomicAdd; pre-zeroed).
// Grid 512 blocks x 256 thr; block = 16 frames; 4 waves split D=2048.
// A-frag: x[g0+l15][dbase+quad*8+j] direct from global (fp32->bf16).
// B-frag: Wb[l15][dbase+quad*8+j] contiguous 16B.
// L2-norm commutes with GEMM: logits(xn) = invn * logits(x).
// ---------------------------------------------------------------------------
__global__ __launch_bounds__(256) void k_logits(const float* __restrict__ x,
    const int* __restrict__ lengths, const short* __restrict__ Wb,
    short* __restrict__ aT, float* __restrict__ asum) {
  const int t = threadIdx.x, wv = t >> 6, lane = t & 63;
  const int l15 = lane & 15, quad = lane >> 4;
  const int fg = blockIdx.x;           // 0..511
  const int g0 = fg * 16;              // first frame of block
  const int b  = fg >> 3;              // 8 blocks per batch
  const int m0 = (fg & 7) * 16;        // frame offset within batch
  const int len = lengths[b];

  const float* xrow = x + (size_t)(g0 + l15) * DDIM + wv * 512 + quad * 8;
  const short* w0   = Wb + l15 * DDIM + wv * 512 + quad * 8;
  const short* w1   = w0 + 16 * DDIM;

  f32x4 c0 = {0.f, 0.f, 0.f, 0.f}, c1 = {0.f, 0.f, 0.f, 0.f};
  float ssq = 0.f;
  #pragma unroll
  for (int s = 0; s < 16; ++s) {
    float4 xa = *(const float4*)(xrow + s * 32);
    float4 xc = *(const float4*)(xrow + s * 32 + 4);
    ssq = fmaf(xa.x, xa.x, ssq); ssq = fmaf(xa.y, xa.y, ssq);
    ssq = fmaf(xa.z, xa.z, ssq); ssq = fmaf(xa.w, xa.w, ssq);
    ssq = fmaf(xc.x, xc.x, ssq); ssq = fmaf(xc.y, xc.y, ssq);
    ssq = fmaf(xc.z, xc.z, ssq); ssq = fmaf(xc.w, xc.w, ssq);
    bf16x8 A = {f2bf(xa.x), f2bf(xa.y), f2bf(xa.z), f2bf(xa.w),
                f2bf(xc.x), f2bf(xc.y), f2bf(xc.z), f2bf(xc.w)};
    bf16x8 B0 = *(const bf16x8*)(w0 + s * 32);
    bf16x8 B1 = *(const bf16x8*)(w1 + s * 32);
    c0 = __builtin_amdgcn_mfma_f32_16x16x32_bf16(A, B0, c0, 0, 0, 0);
    c1 = __builtin_amdgcn_mfma_f32_16x16x32_bf16(A, B1, c1, 0, 0, 0);
  }

  // ssq: lane's partial covers frame g0+l15 at its quad's d-offsets
  ssq += __shfl_xor(ssq, 16, 64);
  ssq += __shfl_xor(ssq, 32, 64);
  __shared__ float sq[4][16];
  __shared__ float lg[4][16][33];
  if (quad == 0) sq[wv][l15] = ssq;
  // C layout: row(frame) = quad*4+reg, col(k) = l15
  #pragma unroll
  for (int r = 0; r < 4; ++r) {
    lg[wv][quad * 4 + r][l15]      = c0[r];
    lg[wv][quad * 4 + r][16 + l15] = c1[r];
  }
  __syncthreads();

  // reduction/softmax phase: 16 threads per frame, 2 clusters each
  const int fr = t >> 4, kk = (t & 15) * 2;
  float s0 = 0.f, s1 = 0.f;
  #pragma unroll
  for (int w = 0; w < 4; ++w) { s0 += lg[w][fr][kk]; s1 += lg[w][fr][kk + 1]; }
  float ss  = sq[0][fr] + sq[1][fr] + sq[2][fr] + sq[3][fr];
  float inv = 1.f / fmaxf(sqrtf(ss), 1e-12f);
  s0 *= inv; s1 *= inv;
  float mx = fmaxf(s0, s1);
  mx = fmaxf(mx, __shfl_xor(mx, 1, 64));
  mx = fmaxf(mx, __shfl_xor(mx, 2, 64));
  mx = fmaxf(mx, __shfl_xor(mx, 4, 64));
  mx = fmaxf(mx, __shfl_xor(mx, 8, 64));
  float e0 = __expf(s0 - mx), e1 = __expf(s1 - mx);
  float se = e0 + e1;
  se += __shfl_xor(se, 1, 64);
  se += __shfl_xor(se, 2, 64);
  se += __shfl_xor(se, 4, 64);
  se += __shfl_xor(se, 8, 64);
  const bool valid = (m0 + fr) < len;
  float rr = valid ? (1.f / se) : 0.f;
  float a0 = e0 * rr, a1 = e1 * rr;

  __syncthreads();                    // done reading lg; reuse for asum
  lg[0][fr][kk] = a0; lg[0][fr][kk + 1] = a1;
  __syncthreads();
  if (t < KK) {
    float s = 0.f;
    #pragma unroll
    for (int f = 0; f < 16; ++f) s += lg[0][f][t];
    atomicAdd(asum + b * KK + t, s);
  }
  // a' = a * invn, transposed store [b][k][m]
  short* ap = aT + (size_t)b * KK * MM + m0 + fr;
  ap[(size_t)kk * MM]       = f2bf(a0 * inv);
  ap[(size_t)(kk + 1) * MM] = f2bf(a1 * inv);
}

// ---------------------------------------------------------------------------
// K2: vlad GEMM (bf16 MFMA): vlad[k][d] = sum_m a'[m][k] * x[m][d], fused
// avgpool (masked, fp32) + asum*C subtraction + per-cluster ssq.
// Grid (8 d-chunks, 64 b) x 256; wave tile M=32 (2 k-tiles) x N=64 (4 d-tiles).
// A from a'T (contiguous 16B); B = x via 8 strided dword loads/lane + cvt.
// ---------------------------------------------------------------------------
__global__ __launch_bounds__(256) void k_vlad(const float* __restrict__ x,
    const int* __restrict__ lengths, const float* __restrict__ Cc,
    const short* __restrict__ aT, const float* __restrict__ asum,
    float* __restrict__ out, float* __restrict__ ssq_part) {
  const int t = threadIdx.x, wv = t >> 6, lane = t & 63;
  const int l15 = lane & 15, quad = lane >> 4;
  const int dc = blockIdx.x, b = blockIdx.y;
  const int d0 = dc * 256 + wv * 64;
  const int len = lengths[b];
  const float* xb = x + (size_t)b * MM * DDIM;
  const short* at0 = aT + (size_t)b * KK * MM + l15 * MM + quad * 8;

  f32x4 acc[2][4];
  #pragma unroll
  for (int kt = 0; kt < 2; ++kt)
    #pragma unroll
    for (int nt = 0; nt < 4; ++nt) acc[kt][nt] = (f32x4){0.f, 0.f, 0.f, 0.f};
  float avg[4] = {0.f, 0.f, 0.f, 0.f};

  #pragma unroll
  for (int ms = 0; ms < 4; ++ms) {
    const int m0 = ms * 32;
    bf16x8 A0 = *(const bf16x8*)(at0 + m0);
    bf16x8 A1 = *(const bf16x8*)(at0 + 16 * MM + m0);
    #pragma unroll
    for (int nt = 0; nt < 4; ++nt) {
      const float* xc = xb + (size_t)(m0 + quad * 8) * DDIM + d0 + nt * 16 + l15;
      float xv[8];
      #pragma unroll
      for (int j = 0; j < 8; ++j) xv[j] = xc[(size_t)j * DDIM];
      #pragma unroll
      for (int j = 0; j < 8; ++j)
        avg[nt] += (m0 + quad * 8 + j < len) ? xv[j] : 0.f;
      bf16x8 B = {f2bf(xv[0]), f2bf(xv[1]), f2bf(xv[2]), f2bf(xv[3]),
                  f2bf(xv[4]), f2bf(xv[5]), f2bf(xv[6]), f2bf(xv[7])};
      acc[0][nt] = __builtin_amdgcn_mfma_f32_16x16x32_bf16(A0, B, acc[0][nt], 0, 0, 0);
      acc[1][nt] = __builtin_amdgcn_mfma_f32_16x16x32_bf16(A1, B, acc[1][nt], 0, 0, 0);
    }
  }

  // avgpool: each (m,d) touched exactly once per block; reduce over quads
  #pragma unroll
  for (int nt = 0; nt < 4; ++nt) {
    float a = avg[nt];
    a += __shfl_xor(a, 16, 64);
    a += __shfl_xor(a, 32, 64);
    if (quad == 0) out[(size_t)b * OUTROW + d0 + nt * 16 + l15] = a / (float)len;
  }

  __shared__ float ssw[4][33];
  float* orow = out + (size_t)b * OUTROW + DDIM;
  #pragma unroll
  for (int kt = 0; kt < 2; ++kt) {
    #pragma unroll
    for (int r = 0; r < 4; ++r) {
      const int k = kt * 16 + quad * 4 + r;
      const float as = asum[b * KK + k];
      float sqv = 0.f;
      #pragma unroll
      for (int nt = 0; nt < 4; ++nt) {
        const int d = d0 + nt * 16 + l15;
        float v = acc[kt][nt][r] - as * Cc[(size_t)k * DDIM + d];
        orow[(size_t)k * DDIM + d] = v;
        sqv = fmaf(v, v, sqv);
      }
      sqv += __shfl_xor(sqv, 1, 64);
      sqv += __shfl_xor(sqv, 2, 64);
      sqv += __shfl_xor(sqv, 4, 64);
      sqv += __shfl_xor(sqv, 8, 64);
      if (l15 == 0) ssw[wv][k] = sqv;
    }
  }
  __syncthreads();
  if (t < KK)
    ssq_part[((size_t)dc * BB + b) * KK + t] =
        ssw[0][t] + ssw[1][t] + ssw[2][t] + ssw[3][t];
}

// ---------------------------------------------------------------------------
// K3: fused scales + apply (unchanged from r4). grid (32 k, 64 b) x 256.
// ---------------------------------------------------------------------------
__global__ __launch_bounds__(256) void k_norm(const float* __restrict__ ssq_part,
    float* __restrict__ out) {
  const int t = threadIdx.x;
  const int k = blockIdx.x;
  const int b = blockIdx.y;
  __shared__ float ssk[32];
  if (t < 32) {
    float sk = 0.f;
    #pragma unroll
    for (int dc = 0; dc < 8; ++dc)
      sk += ssq_part[((size_t)dc * BB + b) * KK + t];
    ssk[t] = sk;
  }
  __syncthreads();
  float gss = 0.f, iv_own = 0.f;
  #pragma unroll
  for (int kk = 0; kk < 32; ++kk) {
    float nk = sqrtf(ssk[kk]);
    float iv = 1.f / fmaxf(nk, 1e-12f);
    float nn = nk * iv;
    gss += nn * nn;
    if (kk == k) iv_own = iv;
  }
  float sc = iv_own / fmaxf(sqrtf(gss), 1e-12f);
  float* row = out + (size_t)b * OUTROW + DDIM + (size_t)k * DDIM;
  #pragma unroll
  for (int h = 0; h < 2; ++h) {
    float4* p = (float4*)(row + h * 1024 + t * 4);
    float4 v = *p;
    v.x *= sc; v.y *= sc; v.z *= sc; v.w *= sc;
    *p = v;
  }
}

// ---------------------------------------------------------------------------
extern "C" void kernel_launch(void* const* d_in, const int* in_sizes, int n_in,
                              void* d_out, int out_size, void* d_ws, size_t ws_size,
                              hipStream_t stream) {
  const float* x       = (const float*)d_in[0];
  const int*   lengths = (const int*)d_in[1];
  const float* W       = (const float*)d_in[2];
  const float* C       = (const float*)d_in[3];
  float* out = (float*)d_out;

  short* Wb   = (short*)d_ws;                         // 32*2048 shorts (128KB)
  short* aT   = Wb + (size_t)KK * DDIM;               // 64*32*128 shorts (512KB)
  float* asum = (float*)(aT + (size_t)BB * KK * MM);  // 64*32
  float* ssqp = asum + (size_t)BB * KK;               // 8*64*32

  hipMemsetAsync(asum, 0, (size_t)BB * KK * sizeof(float), stream);
  k_prep  <<<dim3(32),      256, 0, stream>>>(W, Wb);
  k_logits<<<dim3(512),     256, 0, stream>>>(x, lengths, Wb, aT, asum);
  k_vlad  <<<dim3(8, BB),   256, 0, stream>>>(x, lengths, C, aT, asum, out, ssqp);
  k_norm  <<<dim3(KK, BB),  256, 0, stream>>>(ssqp, out);
}

// Round 6
// 146.072 us; speedup vs baseline: 1.7064x; 1.0143x over previous
//
#include <hip/hip_runtime.h>
#include <math.h>

#define BB 64
#define MM 128
#define DDIM 2048
#define KK 32
#define NFR (BB*MM)              // 8192
#define OUTROW (DDIM + KK*DDIM)  // 67584

typedef __attribute__((ext_vector_type(8))) short bf16x8;
typedef __attribute__((ext_vector_type(4))) float f32x4;

// float -> bf16 RNE (inputs finite; no NaN handling needed)
__device__ __forceinline__ short f2bf(float f) {
  unsigned u = __builtin_bit_cast(unsigned, f);
  u += 0x7fffu + ((u >> 16) & 1u);
  return (short)(u >> 16);
}
__device__ __forceinline__ unsigned pack2(float lo, float hi) {
  return (unsigned)(unsigned short)f2bf(lo) | ((unsigned)(unsigned short)f2bf(hi) << 16);
}

// ---------------------------------------------------------------------------
// K0: W fp32 -> bf16 once. 65536 elems, 32 blocks x 256 x 8.
// ---------------------------------------------------------------------------
__global__ __launch_bounds__(256) void k_prep(const float* __restrict__ W,
                                              short* __restrict__ Wb) {
  int i = (blockIdx.x * 256 + threadIdx.x) * 8;
  float4 a = *(const float4*)(W + i);
  float4 b = *(const float4*)(W + i + 4);
  bf16x8 o = {f2bf(a.x), f2bf(a.y), f2bf(a.z), f2bf(a.w),
              f2bf(b.x), f2bf(b.y), f2bf(b.z), f2bf(b.w)};
  *(bf16x8*)(Wb + i) = o;
}

// ---------------------------------------------------------------------------
// K1: fused logits GEMM (bf16 MFMA) + per-frame ssq + softmax + mask.
// Writes a'T[b][k][m] bf16 (a' = a * invn, the vlad A-frag layout) and
// asum_p[fg][k] fp32 partials (no atomics, no memset).
// Grid 512 x 256; block = 16 frames; 4 waves split D=2048.
// ---------------------------------------------------------------------------
__global__ __launch_bounds__(256) void k_logits(const float* __restrict__ x,
    const int* __restrict__ lengths, const short* __restrict__ Wb,
    short* __restrict__ aT, float* __restrict__ asum_p) {
  const int t = threadIdx.x, wv = t >> 6, lane = t & 63;
  const int l15 = lane & 15, quad = lane >> 4;
  const int fg = blockIdx.x;           // 0..511
  const int g0 = fg * 16;              // first frame of block
  const int b  = fg >> 3;              // 8 blocks per batch
  const int m0 = (fg & 7) * 16;        // frame offset within batch
  const int len = lengths[b];

  const float* xrow = x + (size_t)(g0 + l15) * DDIM + wv * 512 + quad * 8;
  const short* w0   = Wb + l15 * DDIM + wv * 512 + quad * 8;
  const short* w1   = w0 + 16 * DDIM;

  f32x4 c0 = {0.f, 0.f, 0.f, 0.f}, c1 = {0.f, 0.f, 0.f, 0.f};
  float ssq = 0.f;
  #pragma unroll
  for (int s = 0; s < 16; ++s) {
    float4 xa = *(const float4*)(xrow + s * 32);
    float4 xc = *(const float4*)(xrow + s * 32 + 4);
    ssq = fmaf(xa.x, xa.x, ssq); ssq = fmaf(xa.y, xa.y, ssq);
    ssq = fmaf(xa.z, xa.z, ssq); ssq = fmaf(xa.w, xa.w, ssq);
    ssq = fmaf(xc.x, xc.x, ssq); ssq = fmaf(xc.y, xc.y, ssq);
    ssq = fmaf(xc.z, xc.z, ssq); ssq = fmaf(xc.w, xc.w, ssq);
    bf16x8 A = {f2bf(xa.x), f2bf(xa.y), f2bf(xa.z), f2bf(xa.w),
                f2bf(xc.x), f2bf(xc.y), f2bf(xc.z), f2bf(xc.w)};
    bf16x8 B0 = *(const bf16x8*)(w0 + s * 32);
    bf16x8 B1 = *(const bf16x8*)(w1 + s * 32);
    c0 = __builtin_amdgcn_mfma_f32_16x16x32_bf16(A, B0, c0, 0, 0, 0);
    c1 = __builtin_amdgcn_mfma_f32_16x16x32_bf16(A, B1, c1, 0, 0, 0);
  }

  // ssq partial covers frame g0+l15 at this wave+quad's d-offsets
  ssq += __shfl_xor(ssq, 16, 64);
  ssq += __shfl_xor(ssq, 32, 64);
  __shared__ float sq[4][16];
  __shared__ float lg[4][16][33];
  if (quad == 0) sq[wv][l15] = ssq;
  // C layout: row(frame) = quad*4+reg, col(k) = l15
  #pragma unroll
  for (int r = 0; r < 4; ++r) {
    lg[wv][quad * 4 + r][l15]      = c0[r];
    lg[wv][quad * 4 + r][16 + l15] = c1[r];
  }
  __syncthreads();

  // 16 threads per frame, 2 clusters each
  const int fr = t >> 4, kk = (t & 15) * 2;
  float s0 = 0.f, s1 = 0.f;
  #pragma unroll
  for (int w = 0; w < 4; ++w) { s0 += lg[w][fr][kk]; s1 += lg[w][fr][kk + 1]; }
  float ss  = sq[0][fr] + sq[1][fr] + sq[2][fr] + sq[3][fr];
  float inv = 1.f / fmaxf(sqrtf(ss), 1e-12f);
  s0 *= inv; s1 *= inv;
  float mx = fmaxf(s0, s1);
  mx = fmaxf(mx, __shfl_xor(mx, 1, 64));
  mx = fmaxf(mx, __shfl_xor(mx, 2, 64));
  mx = fmaxf(mx, __shfl_xor(mx, 4, 64));
  mx = fmaxf(mx, __shfl_xor(mx, 8, 64));
  float e0 = __expf(s0 - mx), e1 = __expf(s1 - mx);
  float se = e0 + e1;
  se += __shfl_xor(se, 1, 64);
  se += __shfl_xor(se, 2, 64);
  se += __shfl_xor(se, 4, 64);
  se += __shfl_xor(se, 8, 64);
  const bool valid = (m0 + fr) < len;
  float rr = valid ? (1.f / se) : 0.f;
  float a0 = e0 * rr, a1 = e1 * rr;

  __syncthreads();                    // done reading lg; reuse for asum
  lg[0][fr][kk] = a0; lg[0][fr][kk + 1] = a1;
  __syncthreads();
  if (t < KK) {
    float s = 0.f;
    #pragma unroll
    for (int f = 0; f < 16; ++f) s += lg[0][f][t];
    asum_p[(size_t)fg * KK + t] = s;   // partial for frames m0..m0+15
  }
  // a' = a * invn, transposed store [b][k][m]
  short* ap = aT + (size_t)b * KK * MM + m0 + fr;
  ap[(size_t)kk * MM]       = f2bf(a0 * inv);
  ap[(size_t)(kk + 1) * MM] = f2bf(a1 * inv);
}

// ---------------------------------------------------------------------------
// K2: vlad GEMM (bf16 MFMA) with coalesced x loads + per-wave LDS transpose.
// Grid (8 dc, 64 b) x 256 (4 waves). Wave owns a 64-d slice; per 32-m chunk:
// stage x float4-coalesced -> bf16 LDS [d][m] (pitch 40 shorts, 16B rows),
// B-frag = one ds_read_b128; A from a'T global (contiguous 16B, L2-hot).
// Fused: avgpool (masked, in staging), asum*C subtract, per-cluster ssq.
// No __syncthreads in main loop (tiles are wave-private).
// ---------------------------------------------------------------------------
__global__ __launch_bounds__(256) void k_vlad(const float* __restrict__ x,
    const int* __restrict__ lengths, const float* __restrict__ Cc,
    const short* __restrict__ aT, const float* __restrict__ asum_p,
    float* __restrict__ out, float* __restrict__ ssq_part) {
  const int t = threadIdx.x, wv = t >> 6, lane = t & 63;
  const int l15 = lane & 15, quad = lane >> 4;
  const int dc = blockIdx.x, b = blockIdx.y;
  const int dw0 = dc * 256 + wv * 64;   // wave d-base
  const int len = lengths[b];

  __shared__ short xbt[4][64][40];      // [wave][d-local][m(32)+pad], rows 80B
  __shared__ float asl[KK];
  __shared__ float ssw[4][33];

  if (t < KK) {
    float s = 0.f;
    #pragma unroll
    for (int p = 0; p < 8; ++p) s += asum_p[(size_t)(b * 8 + p) * KK + t];
    asl[t] = s;
  }

  const float* xb  = x  + (size_t)b * MM * DDIM;
  const short* at0 = aT + (size_t)b * KK * MM + l15 * MM + quad * 8;

  f32x4 acc[2][4];
  #pragma unroll
  for (int kt = 0; kt < 2; ++kt)
    #pragma unroll
    for (int nt = 0; nt < 4; ++nt) acc[kt][nt] = (f32x4){0.f, 0.f, 0.f, 0.f};
  float avg[4] = {0.f, 0.f, 0.f, 0.f};

  const int q4   = l15 * 4;             // lane's 4 staged d-columns
  const int mrow = (lane >> 4) * 2;     // even m within pass group

  for (int ms = 0; ms < 4; ++ms) {
    const int m0 = ms * 32;
    #pragma unroll
    for (int p = 0; p < 4; ++p) {
      int ml = p * 8 + mrow;            // m-local, even
      int m  = m0 + ml;
      const float* xr = xb + (size_t)m * DDIM + dw0 + q4;
      float4 v0 = *(const float4*)xr;          // coalesced 256B/quad-group
      float4 v1 = *(const float4*)(xr + DDIM);
      float f0 = (m < len) ? 1.f : 0.f;
      float f1 = (m + 1 < len) ? 1.f : 0.f;
      avg[0] = fmaf(v0.x, f0, fmaf(v1.x, f1, avg[0]));
      avg[1] = fmaf(v0.y, f0, fmaf(v1.y, f1, avg[1]));
      avg[2] = fmaf(v0.z, f0, fmaf(v1.z, f1, avg[2]));
      avg[3] = fmaf(v0.w, f0, fmaf(v1.w, f1, avg[3]));
      // transposed bf16 store: two m's packed per dword
      *(unsigned*)&xbt[wv][q4 + 0][ml] = pack2(v0.x, v1.x);
      *(unsigned*)&xbt[wv][q4 + 1][ml] = pack2(v0.y, v1.y);
      *(unsigned*)&xbt[wv][q4 + 2][ml] = pack2(v0.z, v1.z);
      *(unsigned*)&xbt[wv][q4 + 3][ml] = pack2(v0.w, v1.w);
    }
    // wave-private tile: same-wave DS ordering is program order, no barrier
    bf16x8 A0 = *(const bf16x8*)(at0 + m0);
    bf16x8 A1 = *(const bf16x8*)(at0 + 16 * MM + m0);
    #pragma unroll
    for (int nt = 0; nt < 4; ++nt) {
      bf16x8 B = *(const bf16x8*)&xbt[wv][nt * 16 + l15][quad * 8];
      acc[0][nt] = __builtin_amdgcn_mfma_f32_16x16x32_bf16(A0, B, acc[0][nt], 0, 0, 0);
      acc[1][nt] = __builtin_amdgcn_mfma_f32_16x16x32_bf16(A1, B, acc[1][nt], 0, 0, 0);
    }
  }

  // avgpool: reduce the 4 m-row groups (lane>>4), lanes 0-15 hold cols q4..q4+3
  #pragma unroll
  for (int c = 0; c < 4; ++c) {
    avg[c] += __shfl_xor(avg[c], 16, 64);
    avg[c] += __shfl_xor(avg[c], 32, 64);
  }
  if (quad == 0) {
    float rl = 1.f / (float)len;
    *(float4*)(out + (size_t)b * OUTROW + dw0 + q4) =
        make_float4(avg[0] * rl, avg[1] * rl, avg[2] * rl, avg[3] * rl);
  }

  __syncthreads();   // asl ready (and all waves done before ssw phase)
  float* orow = out + (size_t)b * OUTROW + DDIM;
  #pragma unroll
  for (int kt = 0; kt < 2; ++kt) {
    #pragma unroll
    for (int r = 0; r < 4; ++r) {
      const int k = kt * 16 + quad * 4 + r;
      const float as = asl[k];
      float sqv = 0.f;
      #pragma unroll
      for (int nt = 0; nt < 4; ++nt) {
        const int d = dw0 + nt * 16 + l15;
        float v = acc[kt][nt][r] - as * Cc[(size_t)k * DDIM + d];
        orow[(size_t)k * DDIM + d] = v;
        sqv = fmaf(v, v, sqv);
      }
      sqv += __shfl_xor(sqv, 1, 64);
      sqv += __shfl_xor(sqv, 2, 64);
      sqv += __shfl_xor(sqv, 4, 64);
      sqv += __shfl_xor(sqv, 8, 64);
      if (l15 == 0) ssw[wv][k] = sqv;
    }
  }
  __syncthreads();
  if (t < KK)
    ssq_part[((size_t)dc * BB + b) * KK + t] =
        ssw[0][t] + ssw[1][t] + ssw[2][t] + ssw[3][t];
}

// ---------------------------------------------------------------------------
// K3: fused scales + apply. grid (32 k, 64 b) x 256.
// ---------------------------------------------------------------------------
__global__ __launch_bounds__(256) void k_norm(const float* __restrict__ ssq_part,
    float* __restrict__ out) {
  const int t = threadIdx.x;
  const int k = blockIdx.x;
  const int b = blockIdx.y;
  __shared__ float ssk[32];
  if (t < 32) {
    float sk = 0.f;
    #pragma unroll
    for (int dc = 0; dc < 8; ++dc)
      sk += ssq_part[((size_t)dc * BB + b) * KK + t];
    ssk[t] = sk;
  }
  __syncthreads();
  float gss = 0.f, iv_own = 0.f;
  #pragma unroll
  for (int kk = 0; kk < 32; ++kk) {
    float nk = sqrtf(ssk[kk]);
    float iv = 1.f / fmaxf(nk, 1e-12f);
    float nn = nk * iv;
    gss += nn * nn;
    if (kk == k) iv_own = iv;
  }
  float sc = iv_own / fmaxf(sqrtf(gss), 1e-12f);
  float* row = out + (size_t)b * OUTROW + DDIM + (size_t)k * DDIM;
  #pragma unroll
  for (int h = 0; h < 2; ++h) {
    float4* p = (float4*)(row + h * 1024 + t * 4);
    float4 v = *p;
    v.x *= sc; v.y *= sc; v.z *= sc; v.w *= sc;
    *p = v;
  }
}

// ---------------------------------------------------------------------------
extern "C" void kernel_launch(void* const* d_in, const int* in_sizes, int n_in,
                              void* d_out, int out_size, void* d_ws, size_t ws_size,
                              hipStream_t stream) {
  const float* x       = (const float*)d_in[0];
  const int*   lengths = (const int*)d_in[1];
  const float* W       = (const float*)d_in[2];
  const float* C       = (const float*)d_in[3];
  float* out = (float*)d_out;

  short* Wb     = (short*)d_ws;                          // 32*2048 shorts
  short* aT     = Wb + (size_t)KK * DDIM;                // 64*32*128 shorts
  float* asum_p = (float*)(aT + (size_t)BB * KK * MM);   // 512*32
  float* ssqp   = asum_p + (size_t)512 * KK;             // 8*64*32

  k_prep  <<<dim3(32),     256, 0, stream>>>(W, Wb);
  k_logits<<<dim3(512),    256, 0, stream>>>(x, lengths, Wb, aT, asum_p);
  k_vlad  <<<dim3(8, BB),  256, 0, stream>>>(x, lengths, C, aT, asum_p, out, ssqp);
  k_norm  <<<dim3(KK, BB), 256, 0, stream>>>(ssqp, out);
}